// Round 14
// baseline (66.926 us; speedup 1.0000x reference)
//
#include <hip/hip_runtime.h>

#define HOP     256
#define WD      32
#define NFRM    4096
#define TLEN    1048832        // FRAMELEN + HOP*(NFRM-1)
#define LROW    786688         // 448 + 4095*192
#define FPB     4              // frames per block (1 wave, 8 chains)
#define XSTR    484            // x floats per frame (121 quads)
#define DSTR    420            // gv floats per chain (105 quads)
#define XQn     121
#define DQn     105
#define XTOT    (FPB*XSTR + 16)
#define GTOT    (8*DSTR + 16)
#define WCLIP   65535.0f

// 8-lane xor-butterfly sum in each aligned 8-lane group; result in all 8.
__device__ __forceinline__ float red8(float v) {
    v += __int_as_float(__builtin_amdgcn_update_dpp(0, __float_as_int(v), 0xB1,  0xF, 0xF, true));
    v += __int_as_float(__builtin_amdgcn_update_dpp(0, __float_as_int(v), 0x4E,  0xF, 0xF, true));
    v += __int_as_float(__builtin_amdgcn_update_dpp(0, __float_as_int(v), 0x141, 0xF, 0xF, true));
    return v;
}
#define CL(v)        __builtin_amdgcn_fmed3f((v), -WCLIP, WCLIP)
#define MAX3(a,b,c)  fmaxf(fmaxf((a),(b)),(c))

// One lag-4 pipelined LMS step (fast path, no clip; clip detected via mx).
// TS: tree-result slot (consumed=s-base for t, rewritten=dot for t+4).
// PS: pend slot (consumed for t, fresh-written for t+4 with lag-4 corr).
// PU1..3: pend slots for t+1..t+3 (lags 1..3).
// WXk = x[t+8c+k] (w-update window), BXk = x[t+4+8c+k] (base-dot window),
// TFm = x[t+m], LFm = x[t+64+m] (frame scalars for the corr slide).
#define STEP1F(TS, PS, PU1, PU2, PU3, GV, IND, \
    WX0,WX1,WX2,WX3,WX4,WX5,WX6,WX7, \
    BX0,BX1,BX2,BX3,BX4,BX5,BX6,BX7, \
    TF0,TF1,TF2,TF3,TF4, LF0,LF1,LF2,LF3,LF4) do {            \
    float s_  = TS + PS;                                      \
    float gm_ = fmaf(-0.05f, s_, (GV));                       \
    so = fmaf((IND), s_,  so);                                \
    eo = fmaf((IND), gm_, eo);                                \
    PU1 = fmaf(gm_, c1, PU1);                                 \
    PU2 = fmaf(gm_, c2, PU2);                                 \
    PU3 = fmaf(gm_, c3, PU3);                                 \
    PS  = gm_ * c4;                                           \
    float pd_ = w0 * (BX0);                                   \
    pd_ = fmaf(w1, (BX1), pd_);                               \
    pd_ = fmaf(w2, (BX2), pd_);                               \
    pd_ = fmaf(w3, (BX3), pd_);                               \
    float pe_ = w4 * (BX4);                                   \
    pe_ = fmaf(w5, (BX5), pe_);                               \
    pe_ = fmaf(w6, (BX6), pe_);                               \
    pe_ = fmaf(w7, (BX7), pe_);                               \
    TS  = red8(pd_ + pe_);       /* base for step t+4 (uses pre-update w) */ \
    w0 = fmaf(gm_, (WX0), w0);                                \
    w1 = fmaf(gm_, (WX1), w1);                                \
    w2 = fmaf(gm_, (WX2), w2);                                \
    w3 = fmaf(gm_, (WX3), w3);                                \
    w4 = fmaf(gm_, (WX4), w4);                                \
    w5 = fmaf(gm_, (WX5), w5);                                \
    w6 = fmaf(gm_, (WX6), w6);                                \
    w7 = fmaf(gm_, (WX7), w7);                                \
    mx = MAX3(mx, fabsf(w0), fabsf(w1));                      \
    mx = MAX3(mx, fabsf(w2), fabsf(w3));                      \
    mx = MAX3(mx, fabsf(w4), fabsf(w5));                      \
    mx = MAX3(mx, fabsf(w6), fabsf(w7));                      \
    c1 = fmaf((LF0), (LF1), c1);  c1 = fmaf(-(TF0), (TF1), c1); \
    c2 = fmaf((LF0), (LF2), c2);  c2 = fmaf(-(TF0), (TF2), c2); \
    c3 = fmaf((LF0), (LF3), c3);  c3 = fmaf(-(TF0), (TF3), c3); \
    c4 = fmaf((LF0), (LF4), c4);  c4 = fmaf(-(TF0), (TF4), c4); \
} while (0)

// 4 steps; QA..QD = per-lane window quads [0..15] rel, TA/TB trailing frame
// quads, LA/LB leading (+64) frame quads, GQ = gv quad.
#define STEP4(QA,QB,QC,QD, TA,TB, LA,LB, GQ, IA,IB,IC,ID) do {            \
    STEP1F(T0,P0, P1,P2,P3, GQ.x, IA,                                     \
        QA.x,QA.y,QA.z,QA.w,QB.x,QB.y,QB.z,QB.w,                          \
        QB.x,QB.y,QB.z,QB.w,QC.x,QC.y,QC.z,QC.w,                          \
        TA.x,TA.y,TA.z,TA.w,TB.x,  LA.x,LA.y,LA.z,LA.w,LB.x);             \
    STEP1F(T1,P1, P2,P3,P0, GQ.y, IB,                                     \
        QA.y,QA.z,QA.w,QB.x,QB.y,QB.z,QB.w,QC.x,                          \
        QB.y,QB.z,QB.w,QC.x,QC.y,QC.z,QC.w,QD.x,                          \
        TA.y,TA.z,TA.w,TB.x,TB.y,  LA.y,LA.z,LA.w,LB.x,LB.y);             \
    STEP1F(T2,P2, P3,P0,P1, GQ.z, IC,                                     \
        QA.z,QA.w,QB.x,QB.y,QB.z,QB.w,QC.x,QC.y,                          \
        QB.z,QB.w,QC.x,QC.y,QC.z,QC.w,QD.x,QD.y,                          \
        TA.z,TA.w,TB.x,TB.y,TB.z,  LA.z,LA.w,LB.x,LB.y,LB.z);             \
    STEP1F(T3,P3, P0,P1,P2, GQ.w, ID,                                     \
        QA.w,QB.x,QB.y,QB.z,QB.w,QC.x,QC.y,QC.z,                          \
        QB.w,QC.x,QC.y,QC.z,QC.w,QD.x,QD.y,QD.z,                          \
        TA.w,TB.x,TB.y,TB.z,TB.w,  LA.w,LB.x,LB.y,LB.z,LB.w);             \
} while (0)

// Exact 64-tap autocorrelations C(t0,g) g=1..4 from per-lane window quads
// XA,XB,XC (covering per-lane offsets [0..11] of window start t0); red8
// across the row completes the 64-tap sum.
#define ANC(XA,XB,XC) do {                                                \
    float a_;                                                             \
    a_ = XA.x*XA.y; a_=fmaf(XA.y,XA.z,a_); a_=fmaf(XA.z,XA.w,a_);         \
    a_=fmaf(XA.w,XB.x,a_); a_=fmaf(XB.x,XB.y,a_); a_=fmaf(XB.y,XB.z,a_);  \
    a_=fmaf(XB.z,XB.w,a_); a_=fmaf(XB.w,XC.x,a_);                         \
    anc1 = red8(a_);                                                      \
    a_ = XA.x*XA.z; a_=fmaf(XA.y,XA.w,a_); a_=fmaf(XA.z,XB.x,a_);         \
    a_=fmaf(XA.w,XB.y,a_); a_=fmaf(XB.x,XB.z,a_); a_=fmaf(XB.y,XB.w,a_);  \
    a_=fmaf(XB.z,XC.x,a_); a_=fmaf(XB.w,XC.y,a_);                         \
    anc2 = red8(a_);                                                      \
    a_ = XA.x*XA.w; a_=fmaf(XA.y,XB.x,a_); a_=fmaf(XA.z,XB.y,a_);         \
    a_=fmaf(XA.w,XB.z,a_); a_=fmaf(XB.x,XB.w,a_); a_=fmaf(XB.y,XC.x,a_);  \
    a_=fmaf(XB.z,XC.y,a_); a_=fmaf(XB.w,XC.z,a_);                         \
    anc3 = red8(a_);                                                      \
    a_ = XA.x*XB.x; a_=fmaf(XA.y,XB.y,a_); a_=fmaf(XA.z,XB.z,a_);         \
    a_=fmaf(XA.w,XB.w,a_); a_=fmaf(XB.x,XC.x,a_); a_=fmaf(XB.y,XC.y,a_);  \
    a_=fmaf(XB.z,XC.z,a_); a_=fmaf(XB.w,XC.w,a_);                         \
    anc4 = red8(a_);                                                      \
} while (0)

// block = 64 threads = 1 wave = 8 chains (L=8) = 4 frames x 2 batches.
// 1024 blocks -> 1 wave/SIMD; issue-bound (chain is off the critical path).
__global__ void __launch_bounds__(64, 1)
lms_kernel(const float* __restrict__ dmat, const float* __restrict__ xvec,
           float* __restrict__ out)
{
    __shared__ __align__(16) float lx[XTOT];
    __shared__ __align__(16) float lg[GTOT];   // 0.05 * d per chain

    const int tid = threadIdx.x;
    const int f0  = blockIdx.x * FPB;

    // ---- stage: 484 x-quads + 840 gv-quads ----
    for (int i = tid; i < 484 + 840; i += 64) {
        if (i < 484) {
            int fr = i / XQn, k = i - fr * XQn;
            ((float4*)lx)[i] =
                *(const float4*)(xvec + (size_t)(f0 + fr) * HOP + 4 * k);
        } else {
            int j2 = i - 484;
            int ch2 = j2 / DQn, k = j2 - ch2 * DQn;
            int b2 = ch2 & 1, fr = ch2 >> 1;
            float4 v = *(const float4*)(dmat + (size_t)b2 * TLEN
                                        + (size_t)(f0 + fr) * HOP + WD + 4 * k);
            float4 g2;
            g2.x = 0.05f * v.x; g2.y = 0.05f * v.y;
            g2.z = 0.05f * v.z; g2.w = 0.05f * v.w;
            ((float4*)lg)[j2] = g2;
        }
    }
    __syncthreads();

    const int lane = tid;
    const int ch   = lane >> 3;            // chain 0..7
    const int col  = lane & 7;             // taps 8*col .. 8*col+7
    const int fl   = ch >> 1;              // local frame 0..3
    const int b    = ch & 1;               // batch
    const int f    = f0 + fl;
    const bool early = (f == 0);

    const float4* __restrict__ xq = (const float4*)(lx + fl * XSTR + 8 * col);
    const float4* __restrict__ xu = (const float4*)(lx + fl * XSTR);
    const float4* __restrict__ gq = (const float4*)(lg + ch * DSTR);

    float* od = out + (size_t)b * LROW + 32 + (size_t)192 * f;
    float* oe = od + 2 * (size_t)LROW;

    if (blockIdx.x == 0) {
        int pos = tid & 31;
        for (int r2 = tid >> 5; r2 < 4; r2 += 2)
            out[(size_t)r2 * LROW + pos] = 0.0f;
    }

    const float i0 = (col == 0) ? 1.f : 0.f, i1 = (col == 1) ? 1.f : 0.f;
    const float i2 = (col == 2) ? 1.f : 0.f, i3 = (col == 3) ? 1.f : 0.f;
    const float i4 = (col == 4) ? 1.f : 0.f, i5 = (col == 5) ? 1.f : 0.f;
    const float i6 = (col == 6) ? 1.f : 0.f, i7 = (col == 7) ? 1.f : 0.f;

    float w0=0.f,w1=0.f,w2=0.f,w3=0.f,w4=0.f,w5=0.f,w6=0.f,w7=0.f;
    float ws0=0.f,ws1=0.f,ws2=0.f,ws3=0.f,ws4=0.f,ws5=0.f,ws6=0.f,ws7=0.f;
    float P0=0.f,P1=0.f,P2=0.f,P3=0.f, T0=0.f,T1=0.f,T2=0.f,T3=0.f;
    float so=0.f, eo=0.f, mx=0.f;
    float c1,c2,c3,c4, anc1,anc2,anc3,anc4;
    int  ts = 0;
    bool trig = false;

    float4 X0 = xq[0], X1 = xq[1], X2 = xq[2], X3 = xq[3];
    float4 TQa = xu[0],  TQb = xu[1];
    float4 LQa = xu[16], LQb = xu[17];
    float4 GQa = gq[0],  GQb = gq[1];

    ANC(X0, X1, X2);               // C(0,g) exact
    c1 = anc1; c2 = anc2; c3 = anc3; c4 = anc4;

    #pragma unroll 1
    for (int j = 0; j < 26; ++j) {
        const bool st = (j >= 14) || early;

        STEP4(X0,X1,X2,X3, TQa,TQb, LQa,LQb, GQa, i0,i1,i2,i3);
        TQa = xu[4*j+2]; LQa = xu[4*j+18]; GQa = gq[4*j+2]; X0 = xq[4*j+4];

        STEP4(X1,X2,X3,X0, TQb,TQa, LQb,LQa, GQb, i4,i5,i6,i7);
        TQb = xu[4*j+3]; LQb = xu[4*j+19]; GQb = gq[4*j+3]; X1 = xq[4*j+5];

        if (__any(mx > WCLIP)) { ts = 16*j; trig = true; break; }
        if (st) { od[16*j + col] = so; oe[16*j + col] = 20.0f * eo; }
        so = 0.f; eo = 0.f; mx = 0.f;
        ws0=w0; ws1=w1; ws2=w2; ws3=w3; ws4=w4; ws5=w5; ws6=w6; ws7=w7;

        STEP4(X2,X3,X0,X1, TQa,TQb, LQa,LQb, GQa, i0,i1,i2,i3);
        TQa = xu[4*j+4]; LQa = xu[4*j+20]; GQa = gq[4*j+4]; X2 = xq[4*j+6];

        ANC(X0, X1, X2);           // exact re-anchor of C for next group

        STEP4(X3,X0,X1,X2, TQb,TQa, LQb,LQa, GQb, i4,i5,i6,i7);
        TQb = xu[4*j+5]; LQb = xu[4*j+21]; GQb = gq[4*j+5]; X3 = xq[4*j+7];

        if (__any(mx > WCLIP)) { ts = 16*j + 8; trig = true; break; }
        if (st) { od[16*j+8 + col] = so; oe[16*j+8 + col] = 20.0f * eo; }
        so = 0.f; eo = 0.f; mx = 0.f;
        ws0=w0; ws1=w1; ws2=w2; ws3=w3; ws4=w4; ws5=w5; ws6=w6; ws7=w7;
        c1 = anc1; c2 = anc2; c3 = anc3; c4 = anc4;
    }
    if (!trig) return;

    // ---- cold path: clip engaged; restore snapshot, run exact slow loop ----
    w0=ws0; w1=ws1; w2=ws2; w3=ws3; w4=ws4; w5=ws5; w6=ws6; w7=ws7;
    so = 0.f; eo = 0.f;
    {
        const float* __restrict__ xs = lx + fl * XSTR + 8 * col;
        const float* __restrict__ gs = lg + ch * DSTR;
        #pragma unroll 1
        for (int t = ts; t < 416; ++t) {
            float x0=xs[t+0],x1=xs[t+1],x2=xs[t+2],x3=xs[t+3];
            float x4=xs[t+4],x5=xs[t+5],x6=xs[t+6],x7=xs[t+7];
            float pA = w0*x0; pA=fmaf(w1,x1,pA); pA=fmaf(w2,x2,pA); pA=fmaf(w3,x3,pA);
            float pB = w4*x4; pB=fmaf(w5,x5,pB); pB=fmaf(w6,x6,pB); pB=fmaf(w7,x7,pB);
            float s  = red8(pA + pB);
            float gv = gs[t];
            float gm = fmaf(-0.05f, s, gv);
            float ind = (col == (t & 7)) ? 1.f : 0.f;
            so = fmaf(ind, s, so); eo = fmaf(ind, gm, eo);
            w0 = CL(fmaf(gm,x0,w0)); w1 = CL(fmaf(gm,x1,w1));
            w2 = CL(fmaf(gm,x2,w2)); w3 = CL(fmaf(gm,x3,w3));
            w4 = CL(fmaf(gm,x4,w4)); w5 = CL(fmaf(gm,x5,w5));
            w6 = CL(fmaf(gm,x6,w6)); w7 = CL(fmaf(gm,x7,w7));
            if ((t & 7) == 7) {
                if ((t >> 3) >= 28 || early) {
                    od[t-7+col] = so; oe[t-7+col] = 20.0f * eo;
                }
                so = 0.f; eo = 0.f;
            }
        }
    }
}

extern "C" void kernel_launch(void* const* d_in, const int* in_sizes, int n_in,
                              void* d_out, int out_size, void* d_ws, size_t ws_size,
                              hipStream_t stream) {
    const float* dmat = (const float*)d_in[0];   // (2, TLEN)
    const float* xvec = (const float*)d_in[1];   // (TLEN,)
    float* out = (float*)d_out;                  // [d_est(2,LROW), e(2,LROW)]

    hipLaunchKernelGGL(lms_kernel, dim3(NFRM / FPB), dim3(64), 0, stream,
                       dmat, xvec, out);
}

// Round 15
// 45.912 us; speedup vs baseline: 1.4577x; 1.4577x over previous
//
#include <hip/hip_runtime.h>

#define HOP     256
#define WD      32
#define NFRM    4096
#define TLEN    1048832        // FRAMELEN + HOP*(NFRM-1)
#define LROW    786688         // 448 + 4095*192
#define XSTR    484            // x floats per frame (121 quads; 484 % 32 == 4)
#define DSTR    420            // g floats per chain (105 quads; 420 % 32 == 4)
#define XQn     121
#define DQn     105
#define XTOT    (2*XSTR + 16)  // 984  (+guard for dead prefetch overrun)
#define GTOT    (4*DSTR + 8)   // 1688

// plain DPP move (no add folded in): independent movs of the same source
// pipeline at issue rate — only the first pays the operand-readiness stall.
template<int C>
__device__ __forceinline__ float dppmov(float v) {
    return __int_as_float(
        __builtin_amdgcn_update_dpp(0, __float_as_int(v), C, 0xF, 0xF, true));
}

// 16-lane sum in each row of 16, RADIX-4: two levels of {3 parallel DPP movs
// + 2-deep add tree} instead of four dependent DPP-add hops.
__device__ __forceinline__ float red16(float v) {
    float t1 = dppmov<0xB1>(v);    // quad_perm [1,0,3,2]
    float t2 = dppmov<0x4E>(v);    // quad_perm [2,3,0,1]
    float t3 = dppmov<0x1B>(v);    // quad_perm [3,2,1,0]
    float q  = (v + t1) + (t2 + t3);    // quad sum, uniform within quad
    float u1 = dppmov<0x124>(q);   // row_ror:4
    float u2 = dppmov<0x128>(q);   // row_ror:8
    float u3 = dppmov<0x12C>(q);   // row_ror:12
    return (q + u1) + (u2 + u3);        // row sum, uniform within row
}

#define CL(v) __builtin_amdgcn_fmed3f((v), -65535.0f, 65535.0f)

// One LMS step. GV = 0.05*d (pre-scaled). gm = fmaf(-0.05, s, GV) = 0.05*e.
// Capture: so += IND * s  (IND is 1.0 in exactly one lane's step per 16).
#define STEP1(Xa,Xb,Xc,Xd, GV, IND) do {                          \
    float p = w0 * (Xa);                                          \
    p = fmaf(w1, (Xb), p);                                        \
    p = fmaf(w2, (Xc), p);                                        \
    p = fmaf(w3, (Xd), p);                                        \
    float s  = red16(p);                                          \
    so = fmaf((IND), s, so);                                      \
    float gm = fmaf(-0.05f, s, (GV));                             \
    w0 = CL(fmaf(gm, (Xa), w0));                                  \
    w1 = CL(fmaf(gm, (Xb), w1));                                  \
    w2 = CL(fmaf(gm, (Xc), w2));                                  \
    w3 = CL(fmaf(gm, (Xd), w3));                                  \
} while (0)

#define GROUP4(QA, QB, GQ, Ia, Ib, Ic, Id) do {                   \
    STEP1(QA.x,QA.y,QA.z,QA.w, GQ.x, Ia);                         \
    STEP1(QA.y,QA.z,QA.w,QB.x, GQ.y, Ib);                         \
    STEP1(QA.z,QA.w,QB.x,QB.y, GQ.z, Ic);                         \
    STEP1(QA.w,QB.x,QB.y,QB.z, GQ.w, Id);                         \
} while (0)

// block = 64 threads = 1 wave = 4 chains (L=16) = 2 frames x 2 batches.
// 2048 blocks -> 2 waves/SIMD resident.
__global__ void __launch_bounds__(64, 2)
lms_kernel(const float* __restrict__ dmat, const float* __restrict__ xvec,
           float* __restrict__ out)
{
    __shared__ __align__(16) float lx[XTOT];
    __shared__ __align__(16) float lg[GTOT];   // 0.05 * d, per chain

    const int tid = threadIdx.x;
    const int f0  = blockIdx.x * 2;

    // ---- stage: 242 x-quads + 420 g-quads ----
    for (int i = tid; i < 242 + 420; i += 64) {
        if (i < 242) {
            int fr = (i >= XQn) ? 1 : 0;
            int k  = i - fr * XQn;
            ((float4*)lx)[i] =
                *(const float4*)(xvec + (size_t)(f0 + fr) * HOP + 4 * k);
        } else {
            int j   = i - 242;
            int idx = j / DQn, k = j - idx * DQn;   // idx = b*2 + r
            int b = idx >> 1, r = idx & 1;
            float4 v = *(const float4*)(dmat + (size_t)b * TLEN
                                        + (size_t)(f0 + r) * HOP + WD + 4 * k);
            float4 g2;
            g2.x = 0.05f * v.x; g2.y = 0.05f * v.y;
            g2.z = 0.05f * v.z; g2.w = 0.05f * v.w;
            ((float4*)lg)[j] = g2;
        }
    }
    __syncthreads();

    const int lane = tid & 63;
    const int row  = lane >> 4;            // 0..3
    const int col  = lane & 15;            // taps 4*col .. 4*col+3
    const int fl   = row >> 1;             // local frame 0..1
    const int b    = row & 1;              // batch
    const int f    = f0 + fl;              // global frame
    const bool early = (f == 0);
    const int ci   = b * 2 + fl;           // chain slot in lg

    const float4* __restrict__ xq  = (const float4*)(lx + fl * XSTR + 4 * col);
    const float4* __restrict__ gq  = (const float4*)(lg + ci * DSTR);
    const float*  __restrict__ lgs = lg + ci * DSTR;

    float* od = out + (size_t)b * LROW + 32 + (size_t)192 * f;
    float* oe = od + 2 * (size_t)LROW;

    // leading 32 zeros of the 4 output rows
    if (blockIdx.x == 0) {
        int pos = tid & 31;
        for (int r2 = tid >> 5; r2 < 4; r2 += 2)
            out[(size_t)r2 * LROW + pos] = 0.0f;
    }

    // per-lane step indicators (statically indexed -> registers)
    const float i0  = (col ==  0) ? 1.f : 0.f, i1  = (col ==  1) ? 1.f : 0.f;
    const float i2  = (col ==  2) ? 1.f : 0.f, i3  = (col ==  3) ? 1.f : 0.f;
    const float i4  = (col ==  4) ? 1.f : 0.f, i5  = (col ==  5) ? 1.f : 0.f;
    const float i6  = (col ==  6) ? 1.f : 0.f, i7  = (col ==  7) ? 1.f : 0.f;
    const float i8  = (col ==  8) ? 1.f : 0.f, i9  = (col ==  9) ? 1.f : 0.f;
    const float i10 = (col == 10) ? 1.f : 0.f, i11 = (col == 11) ? 1.f : 0.f;
    const float i12 = (col == 12) ? 1.f : 0.f, i13 = (col == 13) ? 1.f : 0.f;
    const float i14 = (col == 14) ? 1.f : 0.f, i15 = (col == 15) ? 1.f : 0.f;

    float w0 = 0.f, w1 = 0.f, w2 = 0.f, w3 = 0.f;

    // prologue: 2-group lead
    float4 X0 = xq[0], X1 = xq[1], X2 = xq[2];
    float4 G0 = gq[0], G1 = gq[1];

    for (int j = 0; j < 26; ++j) {
        const int g = 4 * j;
        float so  = 0.f;
        float gvs = lgs[16 * j + col];             // for the store-time gm

        float4 X3 = xq[g+3];  float4 G2 = gq[g+2];
        GROUP4(X0, X1, G0, i0,  i1,  i2,  i3);

        X0 = xq[g+4];         float4 G3 = gq[g+3];
        GROUP4(X1, X2, G1, i4,  i5,  i6,  i7);

        X1 = xq[g+5];         G0 = gq[g+4];
        GROUP4(X2, X3, G2, i8,  i9,  i10, i11);

        X2 = xq[g+6];         G1 = gq[g+5];
        GROUP4(X3, X0, G3, i12, i13, i14, i15);

        if (j >= 14 || early) {
            float gms = fmaf(-0.05f, so, gvs);     // == in-loop gm bitwise
            od[16 * j + col] = so;                 // d_est
            oe[16 * j + col] = 20.0f * gms;        // e = 20 * (0.05*e)
        }
    }
}

extern "C" void kernel_launch(void* const* d_in, const int* in_sizes, int n_in,
                              void* d_out, int out_size, void* d_ws, size_t ws_size,
                              hipStream_t stream) {
    const float* dmat = (const float*)d_in[0];   // (2, TLEN)
    const float* xvec = (const float*)d_in[1];   // (TLEN,)
    float* out = (float*)d_out;                  // [d_est(2,LROW), e(2,LROW)]

    hipLaunchKernelGGL(lms_kernel, dim3(NFRM / 2), dim3(64), 0, stream,
                       dmat, xvec, out);
}

// Round 16
// 36.852 us; speedup vs baseline: 1.8161x; 1.2459x over previous
//
#include <hip/hip_runtime.h>

#define HOP     256
#define WD      32
#define NFRM    4096
#define TLEN    1048832        // FRAMELEN + HOP*(NFRM-1)
#define LROW    786688         // 448 + 4095*192
#define XSTR    484            // x floats per frame (121 quads; 484 % 32 == 4)
#define DSTR    420            // g floats per chain (105 quads; 420 % 32 == 4)
#define XQn     121
#define DQn     105
#define XTOT    (2*XSTR + 16)  // 984  (+guard for dead prefetch overrun)
#define GTOT    (4*DSTR + 8)   // 1688

// 16-lane xor-butterfly sum within each row of 16; result in all 16 lanes.
// 4 dependent v_add_f32_dpp hops — measured-optimal (asm-minimal and
// radix-4 variants were null/worse; the ~44cy/hop latency is hardware).
__device__ __forceinline__ float red16(float v) {
    v += __int_as_float(__builtin_amdgcn_update_dpp(0, __float_as_int(v), 0xB1,  0xF, 0xF, true)); // xor1
    v += __int_as_float(__builtin_amdgcn_update_dpp(0, __float_as_int(v), 0x4E,  0xF, 0xF, true)); // xor2
    v += __int_as_float(__builtin_amdgcn_update_dpp(0, __float_as_int(v), 0x141, 0xF, 0xF, true)); // half-mirror
    v += __int_as_float(__builtin_amdgcn_update_dpp(0, __float_as_int(v), 0x140, 0xF, 0xF, true)); // row-mirror
    return v;
}

#define CL(v) __builtin_amdgcn_fmed3f((v), -65535.0f, 65535.0f)

// One LMS step. GV = 0.05*d (pre-scaled). gm = fmaf(-0.05, s, GV) = 0.05*e.
// Capture: so += IND * s  (IND is 1.0 in exactly one lane's step per 16).
#define STEP1(Xa,Xb,Xc,Xd, GV, IND) do {                          \
    float p = w0 * (Xa);                                          \
    p = fmaf(w1, (Xb), p);                                        \
    p = fmaf(w2, (Xc), p);                                        \
    p = fmaf(w3, (Xd), p);                                        \
    float s  = red16(p);                                          \
    so = fmaf((IND), s, so);                                      \
    float gm = fmaf(-0.05f, s, (GV));                             \
    w0 = CL(fmaf(gm, (Xa), w0));                                  \
    w1 = CL(fmaf(gm, (Xb), w1));                                  \
    w2 = CL(fmaf(gm, (Xc), w2));                                  \
    w3 = CL(fmaf(gm, (Xd), w3));                                  \
} while (0)

#define GROUP4(QA, QB, GQ, Ia, Ib, Ic, Id) do {                   \
    STEP1(QA.x,QA.y,QA.z,QA.w, GQ.x, Ia);                         \
    STEP1(QA.y,QA.z,QA.w,QB.x, GQ.y, Ib);                         \
    STEP1(QA.z,QA.w,QB.x,QB.y, GQ.z, Ic);                         \
    STEP1(QA.w,QB.x,QB.y,QB.z, GQ.w, Id);                         \
} while (0)

// block = 64 threads = 1 wave = 4 chains (L=16) = 2 frames x 2 batches.
// 2048 blocks -> 2 waves/SIMD resident; they overlap down to the single
// chain's ~213cy/step serial floor (416 steps x 213cy = 36.9us wall).
__global__ void __launch_bounds__(64, 2)
lms_kernel(const float* __restrict__ dmat, const float* __restrict__ xvec,
           float* __restrict__ out)
{
    __shared__ __align__(16) float lx[XTOT];
    __shared__ __align__(16) float lg[GTOT];   // 0.05 * d, per chain

    const int tid = threadIdx.x;
    const int f0  = blockIdx.x * 2;

    // ---- stage: 242 x-quads + 420 g-quads ----
    for (int i = tid; i < 242 + 420; i += 64) {
        if (i < 242) {
            int fr = (i >= XQn) ? 1 : 0;
            int k  = i - fr * XQn;
            ((float4*)lx)[i] =
                *(const float4*)(xvec + (size_t)(f0 + fr) * HOP + 4 * k);
        } else {
            int j   = i - 242;
            int idx = j / DQn, k = j - idx * DQn;   // idx = b*2 + r
            int b = idx >> 1, r = idx & 1;
            float4 v = *(const float4*)(dmat + (size_t)b * TLEN
                                        + (size_t)(f0 + r) * HOP + WD + 4 * k);
            float4 g2;
            g2.x = 0.05f * v.x; g2.y = 0.05f * v.y;
            g2.z = 0.05f * v.z; g2.w = 0.05f * v.w;
            ((float4*)lg)[j] = g2;
        }
    }
    __syncthreads();

    const int lane = tid & 63;
    const int row  = lane >> 4;            // 0..3
    const int col  = lane & 15;            // taps 4*col .. 4*col+3
    const int fl   = row >> 1;             // local frame 0..1
    const int b    = row & 1;              // batch
    const int f    = f0 + fl;              // global frame
    const bool early = (f == 0);
    const int ci   = b * 2 + fl;           // chain slot in lg

    const float4* __restrict__ xq  = (const float4*)(lx + fl * XSTR + 4 * col);
    const float4* __restrict__ gq  = (const float4*)(lg + ci * DSTR);
    const float*  __restrict__ lgs = lg + ci * DSTR;

    float* od = out + (size_t)b * LROW + 32 + (size_t)192 * f;
    float* oe = od + 2 * (size_t)LROW;

    // leading 32 zeros of the 4 output rows
    if (blockIdx.x == 0) {
        int pos = tid & 31;
        for (int r2 = tid >> 5; r2 < 4; r2 += 2)
            out[(size_t)r2 * LROW + pos] = 0.0f;
    }

    // per-lane step indicators (statically indexed -> registers)
    const float i0  = (col ==  0) ? 1.f : 0.f, i1  = (col ==  1) ? 1.f : 0.f;
    const float i2  = (col ==  2) ? 1.f : 0.f, i3  = (col ==  3) ? 1.f : 0.f;
    const float i4  = (col ==  4) ? 1.f : 0.f, i5  = (col ==  5) ? 1.f : 0.f;
    const float i6  = (col ==  6) ? 1.f : 0.f, i7  = (col ==  7) ? 1.f : 0.f;
    const float i8  = (col ==  8) ? 1.f : 0.f, i9  = (col ==  9) ? 1.f : 0.f;
    const float i10 = (col == 10) ? 1.f : 0.f, i11 = (col == 11) ? 1.f : 0.f;
    const float i12 = (col == 12) ? 1.f : 0.f, i13 = (col == 13) ? 1.f : 0.f;
    const float i14 = (col == 14) ? 1.f : 0.f, i15 = (col == 15) ? 1.f : 0.f;

    float w0 = 0.f, w1 = 0.f, w2 = 0.f, w3 = 0.f;

    // prologue: 2-group lead
    float4 X0 = xq[0], X1 = xq[1], X2 = xq[2];
    float4 G0 = gq[0], G1 = gq[1];

    for (int j = 0; j < 26; ++j) {
        const int g = 4 * j;
        float so  = 0.f;
        float gvs = lgs[16 * j + col];             // for the store-time gm

        float4 X3 = xq[g+3];  float4 G2 = gq[g+2];
        GROUP4(X0, X1, G0, i0,  i1,  i2,  i3);

        X0 = xq[g+4];         float4 G3 = gq[g+3];
        GROUP4(X1, X2, G1, i4,  i5,  i6,  i7);

        X1 = xq[g+5];         G0 = gq[g+4];
        GROUP4(X2, X3, G2, i8,  i9,  i10, i11);

        X2 = xq[g+6];         G1 = gq[g+5];
        GROUP4(X3, X0, G3, i12, i13, i14, i15);

        if (j >= 14 || early) {
            float gms = fmaf(-0.05f, so, gvs);     // == in-loop gm bitwise
            od[16 * j + col] = so;                 // d_est
            oe[16 * j + col] = 20.0f * gms;        // e = 20 * (0.05*e)
        }
    }
}

extern "C" void kernel_launch(void* const* d_in, const int* in_sizes, int n_in,
                              void* d_out, int out_size, void* d_ws, size_t ws_size,
                              hipStream_t stream) {
    const float* dmat = (const float*)d_in[0];   // (2, TLEN)
    const float* xvec = (const float*)d_in[1];   // (TLEN,)
    float* out = (float*)d_out;                  // [d_est(2,LROW), e(2,LROW)]

    hipLaunchKernelGGL(lms_kernel, dim3(NFRM / 2), dim3(64), 0, stream,
                       dmat, xvec, out);
}